// Round 4
// baseline (431.066 us; speedup 1.0000x reference)
//
#include <hip/hip_runtime.h>
#include <hip/hip_bf16.h>
#include <stdint.h>

#define T_SEQ 4096
#define KVB 64
#define BM 128
#define BN 128
#define BK 64
#define SCL2 (0.08838834764831845f * 1.44269504088896340f)

typedef unsigned short u16;
typedef __attribute__((ext_vector_type(8))) short s16x8;
typedef __attribute__((ext_vector_type(4))) short s16x4;
typedef __attribute__((ext_vector_type(4))) float f32x4;

__device__ __forceinline__ u16 f2bf(float f) {
  union { float f; unsigned u; } a; a.f = f;
  unsigned r = a.u + 0x7fffu + ((a.u >> 16) & 1u);
  return (u16)(r >> 16);
}
__device__ __forceinline__ float bf2f(u16 b) {
  union { unsigned u; float f; } a; a.u = ((unsigned)b) << 16;
  return a.f;
}
__device__ __forceinline__ unsigned cvtpk(float lo, float hi) {
  unsigned r;
  asm volatile("v_cvt_pk_bf16_f32 %0, %1, %2" : "=v"(r) : "v"(lo), "v"(hi));
  return r;
}

__device__ __forceinline__ void gl_lds16(const void* g, void* l) {
  __builtin_amdgcn_global_load_lds((const __attribute__((address_space(1))) void*)g,
                                   (__attribute__((address_space(3))) void*)l, 16, 0, 0);
}

// ---------------- fp32 -> bf16 convert (hidden) ----------------
__global__ __launch_bounds__(256) void k_cvt(const float* __restrict__ in, u16* __restrict__ out) {
  int i = (blockIdx.x * 256 + threadIdx.x) * 8;
  const float4* p = (const float4*)(in + i);
  float4 a = p[0], b = p[1];
  s16x8 o;
  o[0] = (short)f2bf(a.x); o[1] = (short)f2bf(a.y); o[2] = (short)f2bf(a.z); o[3] = (short)f2bf(a.w);
  o[4] = (short)f2bf(b.x); o[5] = (short)f2bf(b.y); o[6] = (short)f2bf(b.z); o[7] = (short)f2bf(b.w);
  *(s16x8*)(out + i) = o;
}

// ---------------- transpose + convert weights: out[c][r] = bf16(in[r][c]) ----------------
__global__ __launch_bounds__(256) void k_transpose_cvt(const float* __restrict__ in, u16* __restrict__ out,
                                                       int R, int C) {
  __shared__ float tile[32][33];
  int c0 = blockIdx.x * 32, r0 = blockIdx.y * 32;
  int tx = threadIdx.x & 31, ty = threadIdx.x >> 5;
#pragma unroll
  for (int k = 0; k < 4; k++) tile[ty + 8 * k][tx] = in[(size_t)(r0 + ty + 8 * k) * C + c0 + tx];
  __syncthreads();
#pragma unroll
  for (int k = 0; k < 4; k++) out[(size_t)(c0 + ty + 8 * k) * R + r0 + tx] = f2bf(tile[tx][ty + 8 * k]);
}

// ---------------- GEMM: C[m][n] = sum_k A[m][k]*Bt[n][k]  (A,Bt bf16) ----------------
__global__ __launch_bounds__(256, 2) void k_gemm(const u16* __restrict__ A, const u16* __restrict__ Bt,
                                                 u16* __restrict__ Cq, u16* __restrict__ Ck, u16* __restrict__ Cvt,
                                                 float* __restrict__ Cf, int M, int N, int Kd, int mode) {
  __shared__ u16 SM[BM * BK + BN * BK];
  u16* As = SM;
  u16* Bs = SM + BM * BK;
  int tid = threadIdx.x, lane = tid & 63, w = tid >> 6;
  int g = lane >> 4, r16 = lane & 15;
  int m0 = blockIdx.y * BM, n0 = blockIdx.x * BN;
  int wr = w >> 1, wc = w & 1;
  f32x4 acc[4][4] = {};

  for (int kt = 0; kt < Kd; kt += BK) {
#pragma unroll
    for (int i = 0; i < 4; i++) {
      int idx = i * 256 + tid;
      int row = idx >> 3, c = idx & 7;
      int cs = c ^ (row & 7);
      gl_lds16(A + (size_t)(m0 + row) * Kd + kt + cs * 8, As + (i * 256 + w * 64) * 8);
    }
#pragma unroll
    for (int i = 0; i < 4; i++) {
      int idx = i * 256 + tid;
      int row = idx >> 3, c = idx & 7;
      int cs = c ^ (row & 7);
      gl_lds16(Bt + (size_t)(n0 + row) * Kd + kt + cs * 8, Bs + (i * 256 + w * 64) * 8);
    }
    __syncthreads();
#pragma unroll
    for (int kk = 0; kk < 2; kk++) {
      s16x8 af[4], bfr[4];
#pragma unroll
      for (int mi = 0; mi < 4; mi++) {
        int row = wr * 64 + mi * 16 + r16;
        af[mi] = *(const s16x8*)(As + row * 64 + (((kk * 4 + g) ^ (row & 7)) * 8));
      }
#pragma unroll
      for (int ni = 0; ni < 4; ni++) {
        int row = wc * 64 + ni * 16 + r16;
        bfr[ni] = *(const s16x8*)(Bs + row * 64 + (((kk * 4 + g) ^ (row & 7)) * 8));
      }
#pragma unroll
      for (int mi = 0; mi < 4; mi++)
#pragma unroll
        for (int ni = 0; ni < 4; ni++)
          acc[mi][ni] = __builtin_amdgcn_mfma_f32_16x16x32_bf16(af[mi], bfr[ni], acc[mi][ni], 0, 0, 0);
    }
    __syncthreads();
  }

#pragma unroll
  for (int mi = 0; mi < 4; mi++) {
    int rowb = m0 + wr * 64 + mi * 16 + g * 4;
#pragma unroll
    for (int ni = 0; ni < 4; ni++) {
      int ncol0 = n0 + wc * 64 + ni * 16;
      int col = ncol0 + r16;
      if (mode == 0) {
        if (ncol0 < 2048) {
#pragma unroll
          for (int j = 0; j < 4; j++) Cq[(size_t)(rowb + j) * 2048 + col] = f2bf(acc[mi][ni][j]);
        } else if (ncol0 < 2560) {
#pragma unroll
          for (int j = 0; j < 4; j++) Ck[(size_t)(rowb + j) * 512 + (col - 2048)] = f2bf(acc[mi][ni][j]);
        } else {
          s16x4 pk;
#pragma unroll
          for (int j = 0; j < 4; j++) pk[j] = (short)f2bf(acc[mi][ni][j]);
          *(s16x4*)(Cvt + (size_t)(col - 2560) * T_SEQ + rowb) = pk;
        }
      } else {
#pragma unroll
        for (int j = 0; j < 4; j++) Cf[(size_t)(rowb + j) * N + col] = acc[mi][ni][j];
      }
    }
  }
}

// ---------------- RMSNorm + RoPE (+ fold attention scale into Q) ----------------
__global__ __launch_bounds__(256) void k_normrope(u16* __restrict__ Q, u16* __restrict__ Kc,
                                                  const float* __restrict__ sinT, const float* __restrict__ cosT,
                                                  const float* __restrict__ qsc, const float* __restrict__ ksc) {
  int t = blockIdx.x;
  int w = threadIdx.x >> 6, lane = threadIdx.x & 63;
  int unit = blockIdx.y * 4 + w;  // 0..15 Q heads, 16..19 K heads
  u16* base;
  const float* sc;
  float fold;
  if (unit < 16) { base = Q + (size_t)t * 2048 + unit * 128; sc = qsc; fold = SCL2; }
  else { base = Kc + (size_t)t * 512 + (unit - 16) * 128; sc = ksc; fold = 1.0f; }
  float x1 = bf2f(base[lane]), x2 = bf2f(base[lane + 64]);
  float ss = x1 * x1 + x2 * x2;
#pragma unroll
  for (int off = 32; off >= 1; off >>= 1) ss += __shfl_xor(ss, off);
  float rinv = rsqrtf(ss * (1.0f / 128.0f) + 1e-6f);
  float n1 = x1 * rinv * sc[lane], n2 = x2 * rinv * sc[lane + 64];
  float s = sinT[t * 64 + lane], c = cosT[t * 64 + lane];
  base[lane] = f2bf((n1 * c - n2 * s) * fold);
  base[lane + 64] = f2bf((n2 * c + n1 * s) * fold);
}

// ---------------- Flash attention (causal GQA) — barrier-free single-wave blocks ----------------
// Q [T][2048] bf16 (normed+roped, pre-scaled by SCALE*log2e), Kc [T][512], Vt [512][T], O [T][2048]
// 2048 blocks x 64 threads. Each wave owns 32 q-rows; K/V fragments read directly from L2
// (K+V per XCD = 2 MB, L2-resident). No __syncthreads anywhere. Serpentine-LPT balance per XCD.
__global__ __launch_bounds__(64, 2) void k_attn(const u16* __restrict__ Q, const u16* __restrict__ Kc,
                                                const u16* __restrict__ Vt, u16* __restrict__ O) {
  __shared__ u16 SM[4096];  // 8KB wave-private: P buffer (4KB) / epilogue transpose (8KB)
  int lane = threadIdx.x & 63;
  int g = lane >> 4, r16 = lane & 15;

  // XCD chunking: heads {2*xcd, 2*xcd+1} -> same gh per XCD (K/V L2-resident).
  // Serpentine-LPT across the XCD's 32 CUs: each CU gets 8 waves with balanced total work.
  int bid = blockIdx.x;
  int xcd = bid & 7;
  int s = bid >> 3;          // 0..255 slot within XCD
  int r = s >> 5;            // rank 0..7
  int c = s & 31;            // CU slot 0..31
  int j = r * 32 + ((r & 1) ? (31 - c) : c);
  int h = xcd * 2 + (j & 1);
  int gi = 127 - (j >> 1);   // row-group 0..127, descending work
  int r0 = gi * 32;          // this wave's q rows [r0, r0+32)
  int gh = h >> 2;

  const u16* Kb = Kc + gh * 128;
  const u16* Vb = Vt + (size_t)(gh * 128) * T_SEQ;

  s16x8 qf[2][4];
#pragma unroll
  for (int qc = 0; qc < 2; qc++)
#pragma unroll
    for (int dc = 0; dc < 4; dc++)
      qf[qc][dc] = *(const s16x8*)(Q + (size_t)(r0 + qc * 16 + r16) * 2048 + h * 128 + dc * 32 + g * 8);

  f32x4 acc[2][8] = {};
  float mrun[2] = {-3.0e38f, -3.0e38f};
  float lrun[2] = {0.0f, 0.0f};

  for (int kv0 = 0; kv0 < r0 + 32; kv0 += KVB) {
    // S = K @ Q^T : sv[qc][kc] lane holds key = kv0+kc*16+g*4+reg, q = r0+qc*16+r16
    f32x4 sv[2][4] = {};
    __builtin_amdgcn_s_setprio(1);
#pragma unroll
    for (int kc = 0; kc < 4; kc++) {
      s16x8 kf[4];
#pragma unroll
      for (int dc = 0; dc < 4; dc++)
        kf[dc] = *(const s16x8*)(Kb + (size_t)(kv0 + kc * 16 + r16) * 512 + dc * 32 + g * 8);
#pragma unroll
      for (int dc = 0; dc < 4; dc++) {
        sv[0][kc] = __builtin_amdgcn_mfma_f32_16x16x32_bf16(kf[dc], qf[0][dc], sv[0][kc], 0, 0, 0);
        sv[1][kc] = __builtin_amdgcn_mfma_f32_16x16x32_bf16(kf[dc], qf[1][dc], sv[1][kc], 0, 0, 0);
      }
    }
    __builtin_amdgcn_s_setprio(0);

    // online softmax per q-column set (logits already in log2 units via pre-scaled Q)
#pragma unroll
    for (int qc = 0; qc < 2; qc++) {
      int qg = r0 + qc * 16 + r16;
      bool needmask = (kv0 + KVB - 1) > (r0 + qc * 16);
      if (needmask) {
#pragma unroll
        for (int kc = 0; kc < 4; kc++)
#pragma unroll
          for (int j2 = 0; j2 < 4; j2++)
            if (kv0 + kc * 16 + g * 4 + j2 > qg) sv[qc][kc][j2] = -3.0e38f;
      }
      float mt = sv[qc][0][0];
#pragma unroll
      for (int kc = 0; kc < 4; kc++)
#pragma unroll
        for (int j2 = 0; j2 < 4; j2++) mt = fmaxf(mt, sv[qc][kc][j2]);
      mt = fmaxf(mt, __shfl_xor(mt, 16));
      mt = fmaxf(mt, __shfl_xor(mt, 32));
      // defer-max (T13): only rescale when tile max exceeds running max + 8 (log2 units)
      if (__any(mt > mrun[qc] + 8.0f)) {
        float mnew = fmaxf(mrun[qc], mt);
        float al = exp2f(mrun[qc] - mnew);
        mrun[qc] = mnew;
        lrun[qc] *= al;
#pragma unroll
        for (int df = 0; df < 8; df++) acc[qc][df] = acc[qc][df] * al;
      }
      float rs = 0.0f;
      u16* Pw = SM + qc * 1024;
#pragma unroll
      for (int kc = 0; kc < 4; kc++) {
        float p0 = exp2f(sv[qc][kc][0] - mrun[qc]);
        float p1 = exp2f(sv[qc][kc][1] - mrun[qc]);
        float p2 = exp2f(sv[qc][kc][2] - mrun[qc]);
        float p3 = exp2f(sv[qc][kc][3] - mrun[qc]);
        rs += (p0 + p1) + (p2 + p3);
        uint2 pk;
        pk.x = cvtpk(p0, p1);
        pk.y = cvtpk(p2, p3);
        int slot = (kc * 2 + (g >> 1)) ^ (r16 & 7);
        *(uint2*)((char*)Pw + r16 * 128 + slot * 16 + (g & 1) * 8) = pk;
      }
      rs += __shfl_xor(rs, 16);
      rs += __shfl_xor(rs, 32);
      lrun[qc] += rs;
    }

    // PV: acc[qc][df] lane holds dim = df*16+g*4+reg, q = r16
    __builtin_amdgcn_s_setprio(1);
#pragma unroll
    for (int st = 0; st < 2; st++) {
      s16x8 pf0 = *(const s16x8*)((char*)SM + r16 * 128 + (((st * 4 + g) ^ (r16 & 7)) * 16));
      s16x8 pf1 = *(const s16x8*)((char*)SM + 2048 + r16 * 128 + (((st * 4 + g) ^ (r16 & 7)) * 16));
#pragma unroll
      for (int df = 0; df < 8; df++) {
        s16x8 vf = *(const s16x8*)(Vb + (size_t)(df * 16 + r16) * T_SEQ + kv0 + st * 32 + g * 8);
        acc[0][df] = __builtin_amdgcn_mfma_f32_16x16x32_bf16(vf, pf0, acc[0][df], 0, 0, 0);
        acc[1][df] = __builtin_amdgcn_mfma_f32_16x16x32_bf16(vf, pf1, acc[1][df], 0, 0, 0);
      }
    }
    __builtin_amdgcn_s_setprio(0);
  }

  // epilogue: transpose through wave-private LDS for coalesced global stores (reuses P region)
  char* ob = (char*)SM;
#pragma unroll
  for (int qc = 0; qc < 2; qc++) {
    float linv = 1.0f / lrun[qc];
#pragma unroll
    for (int df = 0; df < 8; df++) {
      s16x4 pk;
#pragma unroll
      for (int j2 = 0; j2 < 4; j2++) pk[j2] = (short)f2bf(acc[qc][df][j2] * linv);
      int row = qc * 16 + r16;
      int c16 = df * 2 + (g >> 1);
      *(s16x4*)(ob + row * 256 + ((c16 ^ (row & 7)) << 4) + (g & 1) * 8) = pk;
    }
  }
#pragma unroll
  for (int i = 0; i < 8; i++) {
    int idx = i * 64 + lane;
    int row = idx >> 4, cc = idx & 15;
    s16x8 v = *(const s16x8*)(ob + row * 256 + ((cc ^ (row & 7)) << 4));
    *(s16x8*)(O + (size_t)(r0 + row) * 2048 + h * 128 + cc * 8) = v;
  }
}

extern "C" void kernel_launch(void* const* d_in, const int* in_sizes, int n_in,
                              void* d_out, int out_size, void* d_ws, size_t ws_size,
                              hipStream_t stream) {
  const float* hidden = (const float*)d_in[0];
  const float* sinT = (const float*)d_in[1];
  const float* cosT = (const float*)d_in[2];
  // d_in[3] = mask (bool tril) — causal hardcoded
  const float* Wq = (const float*)d_in[4];
  const float* Wk = (const float*)d_in[5];
  const float* Wv = (const float*)d_in[6];
  const float* Wo = (const float*)d_in[7];
  const float* qsc = (const float*)d_in[8];
  const float* ksc = (const float*)d_in[9];
  float* out = (float*)d_out;

  char* ws = (char*)d_ws;
  u16* Xb   = (u16*)(ws + 0);          // [4096][2048]      16.78 MB
  u16* Bqkv = (u16*)(ws + 16777216);   // [3072][2048]      12.58 MB
  u16* Wot  = (u16*)(ws + 29360128);   // [2048][2048]       8.39 MB
  u16* Qraw = (u16*)(ws + 37748736);   // [4096][2048]      16.78 MB
  u16* Kraw = (u16*)(ws + 54525952);   // [4096][512]        4.19 MB
  u16* Vt   = (u16*)(ws + 58720256);   // [512][4096]        4.19 MB
  u16* Oat  = (u16*)(ws + 62914560);   // [4096][2048]      16.78 MB  (end 79.7 MB)

  k_cvt<<<dim3(4096), dim3(256), 0, stream>>>(hidden, Xb);
  k_transpose_cvt<<<dim3(64, 64), dim3(256), 0, stream>>>(Wq, Bqkv, 2048, 2048);
  k_transpose_cvt<<<dim3(16, 64), dim3(256), 0, stream>>>(Wk, Bqkv + 2048 * 2048, 2048, 512);
  k_transpose_cvt<<<dim3(16, 64), dim3(256), 0, stream>>>(Wv, Bqkv + 2560 * 2048, 2048, 512);
  k_transpose_cvt<<<dim3(64, 64), dim3(256), 0, stream>>>(Wo, Wot, 2048, 2048);

  k_gemm<<<dim3(24, 32), dim3(256), 0, stream>>>(Xb, Bqkv, Qraw, Kraw, Vt, (float*)nullptr,
                                                 4096, 3072, 2048, 0);
  k_normrope<<<dim3(4096, 5), dim3(256), 0, stream>>>(Qraw, Kraw, sinT, cosT, qsc, ksc);
  k_attn<<<dim3(2048), dim3(64), 0, stream>>>(Qraw, Kraw, Vt, Oat);
  k_gemm<<<dim3(16, 32), dim3(256), 0, stream>>>(Oat, Wot, (u16*)nullptr, (u16*)nullptr, (u16*)nullptr,
                                                 out, 4096, 2048, 2048, 1);
}

// Round 5
// 274.422 us; speedup vs baseline: 1.5708x; 1.5708x over previous
//
#include <hip/hip_runtime.h>
#include <hip/hip_bf16.h>
#include <stdint.h>

#define T_SEQ 4096
#define KVB 64
#define BM 128
#define BN 128
#define BK 64
#define SCL2 (0.08838834764831845f * 1.44269504088896340f)

typedef unsigned short u16;
typedef __attribute__((ext_vector_type(8))) short s16x8;
typedef __attribute__((ext_vector_type(4))) short s16x4;
typedef __attribute__((ext_vector_type(4))) float f32x4;

__device__ __forceinline__ u16 f2bf(float f) {
  union { float f; unsigned u; } a; a.f = f;
  unsigned r = a.u + 0x7fffu + ((a.u >> 16) & 1u);
  return (u16)(r >> 16);
}
__device__ __forceinline__ float bf2f(u16 b) {
  union { unsigned u; float f; } a; a.u = ((unsigned)b) << 16;
  return a.f;
}
__device__ __forceinline__ unsigned cvtpk(float lo, float hi) {
  unsigned r;
  asm volatile("v_cvt_pk_bf16_f32 %0, %1, %2" : "=v"(r) : "v"(lo), "v"(hi));
  return r;
}

__device__ __forceinline__ void gl_lds16(const void* g, void* l) {
  __builtin_amdgcn_global_load_lds((const __attribute__((address_space(1))) void*)g,
                                   (__attribute__((address_space(3))) void*)l, 16, 0, 0);
}

// ---------------- fp32 -> bf16 convert (hidden) ----------------
__global__ __launch_bounds__(256) void k_cvt(const float* __restrict__ in, u16* __restrict__ out) {
  int i = (blockIdx.x * 256 + threadIdx.x) * 8;
  const float4* p = (const float4*)(in + i);
  float4 a = p[0], b = p[1];
  s16x8 o;
  o[0] = (short)f2bf(a.x); o[1] = (short)f2bf(a.y); o[2] = (short)f2bf(a.z); o[3] = (short)f2bf(a.w);
  o[4] = (short)f2bf(b.x); o[5] = (short)f2bf(b.y); o[6] = (short)f2bf(b.z); o[7] = (short)f2bf(b.w);
  *(s16x8*)(out + i) = o;
}

// ---------------- transpose + convert weights: out[c][r] = bf16(in[r][c]) ----------------
__global__ __launch_bounds__(256) void k_transpose_cvt(const float* __restrict__ in, u16* __restrict__ out,
                                                       int R, int C) {
  __shared__ float tile[32][33];
  int c0 = blockIdx.x * 32, r0 = blockIdx.y * 32;
  int tx = threadIdx.x & 31, ty = threadIdx.x >> 5;
#pragma unroll
  for (int k = 0; k < 4; k++) tile[ty + 8 * k][tx] = in[(size_t)(r0 + ty + 8 * k) * C + c0 + tx];
  __syncthreads();
#pragma unroll
  for (int k = 0; k < 4; k++) out[(size_t)(c0 + ty + 8 * k) * R + r0 + tx] = f2bf(tile[tx][ty + 8 * k]);
}

// ---------------- GEMM: C[m][n] = sum_k A[m][k]*Bt[n][k]  (A,Bt bf16) ----------------
__global__ __launch_bounds__(256, 2) void k_gemm(const u16* __restrict__ A, const u16* __restrict__ Bt,
                                                 u16* __restrict__ Cq, u16* __restrict__ Ck, u16* __restrict__ Cvt,
                                                 float* __restrict__ Cf, int M, int N, int Kd, int mode) {
  __shared__ u16 SM[BM * BK + BN * BK];
  u16* As = SM;
  u16* Bs = SM + BM * BK;
  int tid = threadIdx.x, lane = tid & 63, w = tid >> 6;
  int g = lane >> 4, r16 = lane & 15;
  int m0 = blockIdx.y * BM, n0 = blockIdx.x * BN;
  int wr = w >> 1, wc = w & 1;
  f32x4 acc[4][4] = {};

  for (int kt = 0; kt < Kd; kt += BK) {
#pragma unroll
    for (int i = 0; i < 4; i++) {
      int idx = i * 256 + tid;
      int row = idx >> 3, c = idx & 7;
      int cs = c ^ (row & 7);
      gl_lds16(A + (size_t)(m0 + row) * Kd + kt + cs * 8, As + (i * 256 + w * 64) * 8);
    }
#pragma unroll
    for (int i = 0; i < 4; i++) {
      int idx = i * 256 + tid;
      int row = idx >> 3, c = idx & 7;
      int cs = c ^ (row & 7);
      gl_lds16(Bt + (size_t)(n0 + row) * Kd + kt + cs * 8, Bs + (i * 256 + w * 64) * 8);
    }
    __syncthreads();
#pragma unroll
    for (int kk = 0; kk < 2; kk++) {
      s16x8 af[4], bfr[4];
#pragma unroll
      for (int mi = 0; mi < 4; mi++) {
        int row = wr * 64 + mi * 16 + r16;
        af[mi] = *(const s16x8*)(As + row * 64 + (((kk * 4 + g) ^ (row & 7)) * 8));
      }
#pragma unroll
      for (int ni = 0; ni < 4; ni++) {
        int row = wc * 64 + ni * 16 + r16;
        bfr[ni] = *(const s16x8*)(Bs + row * 64 + (((kk * 4 + g) ^ (row & 7)) * 8));
      }
#pragma unroll
      for (int mi = 0; mi < 4; mi++)
#pragma unroll
        for (int ni = 0; ni < 4; ni++)
          acc[mi][ni] = __builtin_amdgcn_mfma_f32_16x16x32_bf16(af[mi], bfr[ni], acc[mi][ni], 0, 0, 0);
    }
    __syncthreads();
  }

#pragma unroll
  for (int mi = 0; mi < 4; mi++) {
    int rowb = m0 + wr * 64 + mi * 16 + g * 4;
#pragma unroll
    for (int ni = 0; ni < 4; ni++) {
      int ncol0 = n0 + wc * 64 + ni * 16;
      int col = ncol0 + r16;
      if (mode == 0) {
        if (ncol0 < 2048) {
#pragma unroll
          for (int j = 0; j < 4; j++) Cq[(size_t)(rowb + j) * 2048 + col] = f2bf(acc[mi][ni][j]);
        } else if (ncol0 < 2560) {
#pragma unroll
          for (int j = 0; j < 4; j++) Ck[(size_t)(rowb + j) * 512 + (col - 2048)] = f2bf(acc[mi][ni][j]);
        } else {
          s16x4 pk;
#pragma unroll
          for (int j = 0; j < 4; j++) pk[j] = (short)f2bf(acc[mi][ni][j]);
          *(s16x4*)(Cvt + (size_t)(col - 2560) * T_SEQ + rowb) = pk;
        }
      } else {
#pragma unroll
        for (int j = 0; j < 4; j++) Cf[(size_t)(rowb + j) * N + col] = acc[mi][ni][j];
      }
    }
  }
}

// ---------------- RMSNorm + RoPE (+ fold attention scale into Q) ----------------
__global__ __launch_bounds__(256) void k_normrope(u16* __restrict__ Q, u16* __restrict__ Kc,
                                                  const float* __restrict__ sinT, const float* __restrict__ cosT,
                                                  const float* __restrict__ qsc, const float* __restrict__ ksc) {
  int t = blockIdx.x;
  int w = threadIdx.x >> 6, lane = threadIdx.x & 63;
  int unit = blockIdx.y * 4 + w;  // 0..15 Q heads, 16..19 K heads
  u16* base;
  const float* sc;
  float fold;
  if (unit < 16) { base = Q + (size_t)t * 2048 + unit * 128; sc = qsc; fold = SCL2; }
  else { base = Kc + (size_t)t * 512 + (unit - 16) * 128; sc = ksc; fold = 1.0f; }
  float x1 = bf2f(base[lane]), x2 = bf2f(base[lane + 64]);
  float ss = x1 * x1 + x2 * x2;
#pragma unroll
  for (int off = 32; off >= 1; off >>= 1) ss += __shfl_xor(ss, off);
  float rinv = rsqrtf(ss * (1.0f / 128.0f) + 1e-6f);
  float n1 = x1 * rinv * sc[lane], n2 = x2 * rinv * sc[lane + 64];
  float s = sinT[t * 64 + lane], c = cosT[t * 64 + lane];
  base[lane] = f2bf((n1 * c - n2 * s) * fold);
  base[lane + 64] = f2bf((n2 * c + n1 * s) * fold);
}

// ---------------- Flash attention (causal GQA) — pipelined double-buffered staging ----------------
// Q [T][2048] bf16 (normed+roped, pre-scaled by SCALE*log2e), Kc [T][512], Vt [512][T], O [T][2048]
// 512 blocks x 256 thr (4 waves x 32 q-rows, QBLK=128). 2 blocks/CU, complementary qb pairing per CU.
// Per tile: STAGE(t+1) issued first, compute(t), single __syncthreads (T3 minimal pipeline).
__global__ __launch_bounds__(256, 2) void k_attn(const u16* __restrict__ Q, const u16* __restrict__ Kc,
                                                 const u16* __restrict__ Vt, u16* __restrict__ O) {
  // bytes: K dbuf 2x16KB | V dbuf 2x16KB | P 4 waves x 2KB = 72KB
  __shared__ u16 SM[36864];
  int tid = threadIdx.x, lane = tid & 63, w = tid >> 6;
  int g = lane >> 4, r16 = lane & 15;

  // XCD chunking (2 heads per XCD -> K/V L2-resident) + complementary qb pairing per CU slot
  int bid = blockIdx.x;
  int xcd = bid & 7;
  int k = bid >> 3;          // 0..63 within XCD
  int slot = k >> 5;         // 0,1
  int c = k & 31;            // CU within XCD (heuristic)
  int h = xcd * 2 + (c & 1);
  int qb = slot ? (31 - (c >> 1)) : (c >> 1);
  int gh = h >> 2;
  int q0 = qb * 128, qw = q0 + w * 32;
  int nt = 2 * qb + 2;

  s16x8 qf[2][4];
#pragma unroll
  for (int qc = 0; qc < 2; qc++)
#pragma unroll
    for (int dc = 0; dc < 4; dc++)
      qf[qc][dc] = *(const s16x8*)(Q + (size_t)(qw + qc * 16 + r16) * 2048 + h * 128 + dc * 32 + g * 8);

  auto STAGE = [&](int bb, int tt) {
    int kv0 = tt * KVB;
    u16* Kb = SM + bb * 8192;
    u16* Vb = SM + 16384 + bb * 8192;
#pragma unroll
    for (int i = 0; i < 4; i++) {
      int idx = i * 256 + tid;
      int row = idx >> 4, cc = idx & 15;
      int cs = cc ^ (row & 7);
      gl_lds16(Kc + (size_t)(kv0 + row) * 512 + gh * 128 + cs * 8, Kb + (i * 256 + w * 64) * 8);
    }
#pragma unroll
    for (int i = 0; i < 4; i++) {
      int idx = i * 256 + tid;
      int row = idx >> 3, cc = idx & 7;
      int cs = cc ^ (row & 7);
      gl_lds16(Vt + (size_t)(gh * 128 + row) * T_SEQ + kv0 + cs * 8, Vb + (i * 256 + w * 64) * 8);
    }
  };

  f32x4 acc[2][8] = {};
  float mrun[2] = {-3.0e38f, -3.0e38f};
  float lrun[2] = {0.0f, 0.0f};

  STAGE(0, 0);
  __syncthreads();

  for (int t = 0; t < nt; ++t) {
    int kv0 = t * KVB;
    int bb = t & 1;
    STAGE(bb ^ 1, (t + 1 < nt) ? t + 1 : 0);  // prefetch next tile (wrap = dummy, unread)

    if (kv0 <= qw + 31) {  // wave-uniform: at least one unmasked key for this wave
      u16* Kb = SM + bb * 8192;
      u16* Vb = SM + 16384 + bb * 8192;
      u16* Pw = SM + 32768 + w * 1024;  // 2KB per wave, one qc at a time

      // S = K @ Q^T : sv[qc][kc] lane holds key = kv0+kc*16+g*4+reg, q = qw+qc*16+r16
      f32x4 sv[2][4] = {};
      __builtin_amdgcn_s_setprio(1);
#pragma unroll
      for (int kc = 0; kc < 4; kc++) {
        int krow = kc * 16 + r16;
#pragma unroll
        for (int dc = 0; dc < 4; dc++) {
          s16x8 kf = *(const s16x8*)(Kb + krow * 128 + (((dc * 4 + g) ^ (krow & 7)) * 8));
          sv[0][kc] = __builtin_amdgcn_mfma_f32_16x16x32_bf16(kf, qf[0][dc], sv[0][kc], 0, 0, 0);
          sv[1][kc] = __builtin_amdgcn_mfma_f32_16x16x32_bf16(kf, qf[1][dc], sv[1][kc], 0, 0, 0);
        }
      }
      __builtin_amdgcn_s_setprio(0);

#pragma unroll
      for (int qc = 0; qc < 2; qc++) {
        // softmax (logits already in log2 units via pre-scaled Q)
        int qg = qw + qc * 16 + r16;
        bool needmask = (kv0 + KVB - 1) > (qw + qc * 16);
        if (needmask) {
#pragma unroll
          for (int kc = 0; kc < 4; kc++)
#pragma unroll
            for (int j2 = 0; j2 < 4; j2++)
              if (kv0 + kc * 16 + g * 4 + j2 > qg) sv[qc][kc][j2] = -3.0e38f;
        }
        float mt = sv[qc][0][0];
#pragma unroll
        for (int kc = 0; kc < 4; kc++)
#pragma unroll
          for (int j2 = 0; j2 < 4; j2++) mt = fmaxf(mt, sv[qc][kc][j2]);
        mt = fmaxf(mt, __shfl_xor(mt, 16));
        mt = fmaxf(mt, __shfl_xor(mt, 32));
        // defer-max (T13): rescale only when tile max exceeds running max + 8 (log2 units)
        if (__any(mt > mrun[qc] + 8.0f)) {
          float mnew = fmaxf(mrun[qc], mt);
          float al = exp2f(mrun[qc] - mnew);
          mrun[qc] = mnew;
          lrun[qc] *= al;
#pragma unroll
          for (int df = 0; df < 8; df++) acc[qc][df] = acc[qc][df] * al;
        }
        float rs = 0.0f;
#pragma unroll
        for (int kc = 0; kc < 4; kc++) {
          float p0 = exp2f(sv[qc][kc][0] - mrun[qc]);
          float p1 = exp2f(sv[qc][kc][1] - mrun[qc]);
          float p2 = exp2f(sv[qc][kc][2] - mrun[qc]);
          float p3 = exp2f(sv[qc][kc][3] - mrun[qc]);
          rs += (p0 + p1) + (p2 + p3);
          uint2 pk;
          pk.x = cvtpk(p0, p1);
          pk.y = cvtpk(p2, p3);
          int pslot = (kc * 2 + (g >> 1)) ^ (r16 & 7);
          *(uint2*)((char*)Pw + r16 * 128 + pslot * 16 + (g & 1) * 8) = pk;
        }
        rs += __shfl_xor(rs, 16);
        rs += __shfl_xor(rs, 32);
        lrun[qc] += rs;

        // PV for this qc: acc[qc][df] lane holds dim = df*16+g*4+reg, q = r16
        __builtin_amdgcn_s_setprio(1);
#pragma unroll
        for (int st = 0; st < 2; st++) {
          s16x8 pf = *(const s16x8*)((char*)Pw + r16 * 128 + (((st * 4 + g) ^ (r16 & 7)) * 16));
#pragma unroll
          for (int df = 0; df < 8; df++) {
            int vrow = df * 16 + r16;
            s16x8 vf = *(const s16x8*)(Vb + vrow * 64 + (((st * 4 + g) ^ (vrow & 7)) * 8));
            acc[qc][df] = __builtin_amdgcn_mfma_f32_16x16x32_bf16(vf, pf, acc[qc][df], 0, 0, 0);
          }
        }
        __builtin_amdgcn_s_setprio(0);
      }
    }
    __syncthreads();
  }

  // epilogue: transpose through wave-private LDS for coalesced global stores
  char* ob = (char*)SM + w * 8192;
#pragma unroll
  for (int qc = 0; qc < 2; qc++) {
    float linv = 1.0f / lrun[qc];
#pragma unroll
    for (int df = 0; df < 8; df++) {
      s16x4 pk;
#pragma unroll
      for (int j2 = 0; j2 < 4; j2++) pk[j2] = (short)f2bf(acc[qc][df][j2] * linv);
      int row = qc * 16 + r16;
      int c16 = df * 2 + (g >> 1);
      *(s16x4*)(ob + row * 256 + ((c16 ^ (row & 7)) << 4) + (g & 1) * 8) = pk;
    }
  }
#pragma unroll
  for (int i = 0; i < 8; i++) {
    int idx = i * 64 + lane;
    int row = idx >> 4, cc = idx & 15;
    s16x8 v = *(const s16x8*)(ob + row * 256 + ((cc ^ (row & 7)) << 4));
    *(s16x8*)(O + (size_t)(qw + row) * 2048 + h * 128 + cc * 8) = v;
  }
}

extern "C" void kernel_launch(void* const* d_in, const int* in_sizes, int n_in,
                              void* d_out, int out_size, void* d_ws, size_t ws_size,
                              hipStream_t stream) {
  const float* hidden = (const float*)d_in[0];
  const float* sinT = (const float*)d_in[1];
  const float* cosT = (const float*)d_in[2];
  // d_in[3] = mask (bool tril) — causal hardcoded
  const float* Wq = (const float*)d_in[4];
  const float* Wk = (const float*)d_in[5];
  const float* Wv = (const float*)d_in[6];
  const float* Wo = (const float*)d_in[7];
  const float* qsc = (const float*)d_in[8];
  const float* ksc = (const float*)d_in[9];
  float* out = (float*)d_out;

  char* ws = (char*)d_ws;
  u16* Xb   = (u16*)(ws + 0);          // [4096][2048]      16.78 MB
  u16* Bqkv = (u16*)(ws + 16777216);   // [3072][2048]      12.58 MB
  u16* Wot  = (u16*)(ws + 29360128);   // [2048][2048]       8.39 MB
  u16* Qraw = (u16*)(ws + 37748736);   // [4096][2048]      16.78 MB
  u16* Kraw = (u16*)(ws + 54525952);   // [4096][512]        4.19 MB
  u16* Vt   = (u16*)(ws + 58720256);   // [512][4096]        4.19 MB
  u16* Oat  = (u16*)(ws + 62914560);   // [4096][2048]      16.78 MB  (end 79.7 MB)

  k_cvt<<<dim3(4096), dim3(256), 0, stream>>>(hidden, Xb);
  k_transpose_cvt<<<dim3(64, 64), dim3(256), 0, stream>>>(Wq, Bqkv, 2048, 2048);
  k_transpose_cvt<<<dim3(16, 64), dim3(256), 0, stream>>>(Wk, Bqkv + 2048 * 2048, 2048, 512);
  k_transpose_cvt<<<dim3(16, 64), dim3(256), 0, stream>>>(Wv, Bqkv + 2560 * 2048, 2048, 512);
  k_transpose_cvt<<<dim3(64, 64), dim3(256), 0, stream>>>(Wo, Wot, 2048, 2048);

  k_gemm<<<dim3(24, 32), dim3(256), 0, stream>>>(Xb, Bqkv, Qraw, Kraw, Vt, (float*)nullptr,
                                                 4096, 3072, 2048, 0);
  k_normrope<<<dim3(4096, 5), dim3(256), 0, stream>>>(Qraw, Kraw, sinT, cosT, qsc, ksc);
  k_attn<<<dim3(512), dim3(256), 0, stream>>>(Qraw, Kraw, Vt, Oat);
  k_gemm<<<dim3(16, 32), dim3(256), 0, stream>>>(Oat, Wot, (u16*)nullptr, (u16*)nullptr, (u16*)nullptr,
                                                 out, 4096, 2048, 2048, 1);
}

// Round 6
// 268.276 us; speedup vs baseline: 1.6068x; 1.0229x over previous
//
#include <hip/hip_runtime.h>
#include <hip/hip_bf16.h>
#include <stdint.h>

#define T_SEQ 4096
#define KVB 64
#define BM 128
#define BN 128
#define BK 64
#define SCL2 (0.08838834764831845f * 1.44269504088896340f)

typedef unsigned short u16;
typedef __attribute__((ext_vector_type(8))) short s16x8;
typedef __attribute__((ext_vector_type(4))) short s16x4;
typedef __attribute__((ext_vector_type(4))) float f32x4;

__device__ __forceinline__ u16 f2bf(float f) {
  union { float f; unsigned u; } a; a.f = f;
  unsigned r = a.u + 0x7fffu + ((a.u >> 16) & 1u);
  return (u16)(r >> 16);
}
__device__ __forceinline__ float bf2f(u16 b) {
  union { unsigned u; float f; } a; a.u = ((unsigned)b) << 16;
  return a.f;
}
__device__ __forceinline__ unsigned cvtpk(float lo, float hi) {
  unsigned r;
  asm volatile("v_cvt_pk_bf16_f32 %0, %1, %2" : "=v"(r) : "v"(lo), "v"(hi));
  return r;
}

__device__ __forceinline__ void gl_lds16(const void* g, void* l) {
  __builtin_amdgcn_global_load_lds((const __attribute__((address_space(1))) void*)g,
                                   (__attribute__((address_space(3))) void*)l, 16, 0, 0);
}

// ---------------- fp32 -> bf16 convert (hidden) ----------------
__global__ __launch_bounds__(256) void k_cvt(const float* __restrict__ in, u16* __restrict__ out) {
  int i = (blockIdx.x * 256 + threadIdx.x) * 8;
  const float4* p = (const float4*)(in + i);
  float4 a = p[0], b = p[1];
  s16x8 o;
  o[0] = (short)f2bf(a.x); o[1] = (short)f2bf(a.y); o[2] = (short)f2bf(a.z); o[3] = (short)f2bf(a.w);
  o[4] = (short)f2bf(b.x); o[5] = (short)f2bf(b.y); o[6] = (short)f2bf(b.z); o[7] = (short)f2bf(b.w);
  *(s16x8*)(out + i) = o;
}

// ---------------- transpose + convert weights: out[c][r] = bf16(in[r][c]) ----------------
__global__ __launch_bounds__(256) void k_transpose_cvt(const float* __restrict__ in, u16* __restrict__ out,
                                                       int R, int C) {
  __shared__ float tile[32][33];
  int c0 = blockIdx.x * 32, r0 = blockIdx.y * 32;
  int tx = threadIdx.x & 31, ty = threadIdx.x >> 5;
#pragma unroll
  for (int k = 0; k < 4; k++) tile[ty + 8 * k][tx] = in[(size_t)(r0 + ty + 8 * k) * C + c0 + tx];
  __syncthreads();
#pragma unroll
  for (int k = 0; k < 4; k++) out[(size_t)(c0 + ty + 8 * k) * R + r0 + tx] = f2bf(tile[tx][ty + 8 * k]);
}

// ---------------- GEMM: C[m][n] = sum_k A[m][k]*Bt[n][k]  (A,Bt bf16) ----------------
__global__ __launch_bounds__(256, 2) void k_gemm(const u16* __restrict__ A, const u16* __restrict__ Bt,
                                                 u16* __restrict__ Cq, u16* __restrict__ Ck, u16* __restrict__ Cvt,
                                                 float* __restrict__ Cf, int M, int N, int Kd, int mode) {
  __shared__ u16 SM[BM * BK + BN * BK];
  u16* As = SM;
  u16* Bs = SM + BM * BK;
  int tid = threadIdx.x, lane = tid & 63, w = tid >> 6;
  int g = lane >> 4, r16 = lane & 15;
  int m0 = blockIdx.y * BM, n0 = blockIdx.x * BN;
  int wr = w >> 1, wc = w & 1;
  f32x4 acc[4][4] = {};

  for (int kt = 0; kt < Kd; kt += BK) {
#pragma unroll
    for (int i = 0; i < 4; i++) {
      int idx = i * 256 + tid;
      int row = idx >> 3, c = idx & 7;
      int cs = c ^ (row & 7);
      gl_lds16(A + (size_t)(m0 + row) * Kd + kt + cs * 8, As + (i * 256 + w * 64) * 8);
    }
#pragma unroll
    for (int i = 0; i < 4; i++) {
      int idx = i * 256 + tid;
      int row = idx >> 3, c = idx & 7;
      int cs = c ^ (row & 7);
      gl_lds16(Bt + (size_t)(n0 + row) * Kd + kt + cs * 8, Bs + (i * 256 + w * 64) * 8);
    }
    __syncthreads();
#pragma unroll
    for (int kk = 0; kk < 2; kk++) {
      s16x8 af[4], bfr[4];
#pragma unroll
      for (int mi = 0; mi < 4; mi++) {
        int row = wr * 64 + mi * 16 + r16;
        af[mi] = *(const s16x8*)(As + row * 64 + (((kk * 4 + g) ^ (row & 7)) * 8));
      }
#pragma unroll
      for (int ni = 0; ni < 4; ni++) {
        int row = wc * 64 + ni * 16 + r16;
        bfr[ni] = *(const s16x8*)(Bs + row * 64 + (((kk * 4 + g) ^ (row & 7)) * 8));
      }
#pragma unroll
      for (int mi = 0; mi < 4; mi++)
#pragma unroll
        for (int ni = 0; ni < 4; ni++)
          acc[mi][ni] = __builtin_amdgcn_mfma_f32_16x16x32_bf16(af[mi], bfr[ni], acc[mi][ni], 0, 0, 0);
    }
    __syncthreads();
  }

#pragma unroll
  for (int mi = 0; mi < 4; mi++) {
    int rowb = m0 + wr * 64 + mi * 16 + g * 4;
#pragma unroll
    for (int ni = 0; ni < 4; ni++) {
      int ncol0 = n0 + wc * 64 + ni * 16;
      int col = ncol0 + r16;
      if (mode == 0) {
        if (ncol0 < 2048) {
#pragma unroll
          for (int j = 0; j < 4; j++) Cq[(size_t)(rowb + j) * 2048 + col] = f2bf(acc[mi][ni][j]);
        } else if (ncol0 < 2560) {
#pragma unroll
          for (int j = 0; j < 4; j++) Ck[(size_t)(rowb + j) * 512 + (col - 2048)] = f2bf(acc[mi][ni][j]);
        } else {
          s16x4 pk;
#pragma unroll
          for (int j = 0; j < 4; j++) pk[j] = (short)f2bf(acc[mi][ni][j]);
          *(s16x4*)(Cvt + (size_t)(col - 2560) * T_SEQ + rowb) = pk;
        }
      } else {
#pragma unroll
        for (int j = 0; j < 4; j++) Cf[(size_t)(rowb + j) * N + col] = acc[mi][ni][j];
      }
    }
  }
}

// ---------------- RMSNorm + RoPE (+ fold attention scale into Q) ----------------
__global__ __launch_bounds__(256) void k_normrope(u16* __restrict__ Q, u16* __restrict__ Kc,
                                                  const float* __restrict__ sinT, const float* __restrict__ cosT,
                                                  const float* __restrict__ qsc, const float* __restrict__ ksc) {
  int t = blockIdx.x;
  int w = threadIdx.x >> 6, lane = threadIdx.x & 63;
  int unit = blockIdx.y * 4 + w;  // 0..15 Q heads, 16..19 K heads
  u16* base;
  const float* sc;
  float fold;
  if (unit < 16) { base = Q + (size_t)t * 2048 + unit * 128; sc = qsc; fold = SCL2; }
  else { base = Kc + (size_t)t * 512 + (unit - 16) * 128; sc = ksc; fold = 1.0f; }
  float x1 = bf2f(base[lane]), x2 = bf2f(base[lane + 64]);
  float ss = x1 * x1 + x2 * x2;
#pragma unroll
  for (int off = 32; off >= 1; off >>= 1) ss += __shfl_xor(ss, off);
  float rinv = rsqrtf(ss * (1.0f / 128.0f) + 1e-6f);
  float n1 = x1 * rinv * sc[lane], n2 = x2 * rinv * sc[lane + 64];
  float s = sinT[t * 64 + lane], c = cosT[t * 64 + lane];
  base[lane] = f2bf((n1 * c - n2 * s) * fold);
  base[lane + 64] = f2bf((n2 * c + n1 * s) * fold);
}

// ---------------- Flash attention (causal GQA) — 2x2 (q-split x key-split) waves ----------------
// Q [T][2048] bf16 (pre-scaled by SCALE*log2e), Kc [T][512], Vt [512][T], O [T][2048]
// 1024 blocks x 256 thr. Block covers QBLK=64 q-rows; wave (qs,ks) owns 32 q-rows x 32-key slice.
// K/V fragment reads per wave drop 52 -> 18 vs q-only split. Pair-merge of key-slices at the end.
// LDS: K dbuf 2x16KB [0,32K) | V dbuf 2x16KB [32K,64K) | P 4x2KB [64K,72K). Post-loop reused as
// ob f32 accum regions [0,64K) + ml exchange @64K.
__global__ __launch_bounds__(256, 2) void k_attn(const u16* __restrict__ Q, const u16* __restrict__ Kc,
                                                 const u16* __restrict__ Vt, u16* __restrict__ O) {
  __shared__ __align__(16) char SMc[73728];
  int tid = threadIdx.x, lane = tid & 63, w = tid >> 6;
  int g = lane >> 4, r16 = lane & 15;
  int qs = w >> 1, ks = w & 1;

  // XCD chunking (2 heads/XCD -> K/V L2-resident) + LPT (long qb first; backfill via 1024>512 resident)
  int bid = blockIdx.x;
  int xcd = bid & 7;
  int lid = bid >> 3;            // 0..127 within XCD
  int h = xcd * 2 + (lid & 1);
  int qb = 63 - (lid >> 1);      // descending work
  int gh = h >> 2;
  int q0 = qb * 64;
  int qwv = q0 + qs * 32;
  int nt = qb + 1;

  s16x8 qf[2][4];
#pragma unroll
  for (int qc = 0; qc < 2; qc++)
#pragma unroll
    for (int dc = 0; dc < 4; dc++)
      qf[qc][dc] = *(const s16x8*)(Q + (size_t)(qwv + qc * 16 + r16) * 2048 + h * 128 + dc * 32 + g * 8);

  auto STAGE = [&](int bb, int tt) {
    int kv0 = tt * KVB;
    u16* Kb = (u16*)(SMc + bb * 16384);
    u16* Vb = (u16*)(SMc + 32768 + bb * 16384);
#pragma unroll
    for (int i = 0; i < 4; i++) {
      int idx = i * 256 + tid;
      int row = idx >> 4, cc = idx & 15;
      int cs = cc ^ (row & 7);
      gl_lds16(Kc + (size_t)(kv0 + row) * 512 + gh * 128 + cs * 8, Kb + (i * 256 + w * 64) * 8);
    }
#pragma unroll
    for (int i = 0; i < 4; i++) {
      int idx = i * 256 + tid;
      int row = idx >> 3, cc = idx & 7;
      int cs = cc ^ (row & 7);
      gl_lds16(Vt + (size_t)(gh * 128 + row) * T_SEQ + kv0 + cs * 8, Vb + (i * 256 + w * 64) * 8);
    }
  };

  f32x4 acc[2][8] = {};
  float mrun[2] = {-3.0e38f, -3.0e38f};
  float lrun[2] = {0.0f, 0.0f};

  STAGE(0, 0);
  __syncthreads();

  for (int t = 0; t < nt; ++t) {
    int kv0 = t * KVB;
    int bb = t & 1;
    STAGE(bb ^ 1, (t + 1 < nt) ? t + 1 : 0);  // prefetch next (wrap = dummy, unread)

    int kvw = kv0 + ks * 32;  // this wave's 32-key slice
    if (kvw <= qwv + 31) {    // wave-uniform causal skip
      u16* Kb = (u16*)(SMc + bb * 16384);
      u16* Vb = (u16*)(SMc + 32768 + bb * 16384);
      char* Pwb = SMc + 65536 + w * 2048;

      // S = K @ Q^T : sv[qc][kc] lane holds key = kvw+kc*16+g*4+reg, q = qwv+qc*16+r16
      f32x4 sv[2][2] = {};
      __builtin_amdgcn_s_setprio(1);
#pragma unroll
      for (int kc = 0; kc < 2; kc++) {
        int krow = ks * 32 + kc * 16 + r16;
#pragma unroll
        for (int dc = 0; dc < 4; dc++) {
          s16x8 kf = *(const s16x8*)((u16*)Kb + krow * 128 + (((dc * 4 + g) ^ (krow & 7)) * 8));
          sv[0][kc] = __builtin_amdgcn_mfma_f32_16x16x32_bf16(kf, qf[0][dc], sv[0][kc], 0, 0, 0);
          sv[1][kc] = __builtin_amdgcn_mfma_f32_16x16x32_bf16(kf, qf[1][dc], sv[1][kc], 0, 0, 0);
        }
      }
      __builtin_amdgcn_s_setprio(0);

#pragma unroll
      for (int qc = 0; qc < 2; qc++) {
        int qg = qwv + qc * 16 + r16;
        bool needmask = (kvw + 31) > (qwv + qc * 16);
        if (needmask) {
#pragma unroll
          for (int kc = 0; kc < 2; kc++)
#pragma unroll
            for (int j2 = 0; j2 < 4; j2++)
              if (kvw + kc * 16 + g * 4 + j2 > qg) sv[qc][kc][j2] = -3.0e38f;
        }
        float mt = sv[qc][0][0];
#pragma unroll
        for (int kc = 0; kc < 2; kc++)
#pragma unroll
          for (int j2 = 0; j2 < 4; j2++) mt = fmaxf(mt, sv[qc][kc][j2]);
        mt = fmaxf(mt, __shfl_xor(mt, 16));
        mt = fmaxf(mt, __shfl_xor(mt, 32));
        // defer-max (T13)
        if (__any(mt > mrun[qc] + 8.0f)) {
          float mnew = fmaxf(mrun[qc], mt);
          float al = exp2f(mrun[qc] - mnew);
          mrun[qc] = mnew;
          lrun[qc] *= al;
#pragma unroll
          for (int df = 0; df < 8; df++) acc[qc][df] = acc[qc][df] * al;
        }
        float rs = 0.0f;
#pragma unroll
        for (int kc = 0; kc < 2; kc++) {
          float p0 = exp2f(sv[qc][kc][0] - mrun[qc]);
          float p1 = exp2f(sv[qc][kc][1] - mrun[qc]);
          float p2 = exp2f(sv[qc][kc][2] - mrun[qc]);
          float p3 = exp2f(sv[qc][kc][3] - mrun[qc]);
          rs += (p0 + p1) + (p2 + p3);
          uint2 pk;
          pk.x = cvtpk(p0, p1);
          pk.y = cvtpk(p2, p3);
          int unit = ((qc << 2) | (kc << 1) | (g >> 1)) ^ (r16 & 7);
          *(uint2*)(Pwb + r16 * 128 + unit * 16 + (g & 1) * 8) = pk;
        }
        rs += __shfl_xor(rs, 16);
        rs += __shfl_xor(rs, 32);
        lrun[qc] += rs;
      }

      // PV: acc[qc][df] lane holds dim = df*16+g*4+reg, q = r16 (keys = this wave's slice)
      __builtin_amdgcn_s_setprio(1);
      s16x8 pf0 = *(const s16x8*)(Pwb + r16 * 128 + (((0 * 4 + g) ^ (r16 & 7)) * 16));
      s16x8 pf1 = *(const s16x8*)(Pwb + r16 * 128 + (((1 * 4 + g) ^ (r16 & 7)) * 16));
#pragma unroll
      for (int df = 0; df < 8; df++) {
        int vrow = df * 16 + r16;
        s16x8 vf = *(const s16x8*)((u16*)Vb + vrow * 64 + (((ks * 4 + g) ^ (vrow & 7)) * 8));
        acc[0][df] = __builtin_amdgcn_mfma_f32_16x16x32_bf16(vf, pf0, acc[0][df], 0, 0, 0);
        acc[1][df] = __builtin_amdgcn_mfma_f32_16x16x32_bf16(vf, pf1, acc[1][df], 0, 0, 0);
      }
      __builtin_amdgcn_s_setprio(0);
    }
    __syncthreads();
  }

  // ---- pair-merge (ks=0 slice + ks=1 slice) + store ----
  float* ml = (float*)(SMc + 65536);  // [4 waves][2 qc][16 r16][2] (P region, dead)
  if (g < 2) {
    float mv = g ? mrun[1] : mrun[0];
    float lv = g ? lrun[1] : lrun[0];
    int mi = ((w * 2 + g) * 16 + r16) * 2;
    ml[mi] = mv;
    ml[mi + 1] = lv;
  }
  __syncthreads();
  int pw = w ^ 1;
  float scale[2];
#pragma unroll
  for (int qc = 0; qc < 2; qc++) {
    float pm = ml[((pw * 2 + qc) * 16 + r16) * 2];
    float pl = ml[((pw * 2 + qc) * 16 + r16) * 2 + 1];
    float ms = fmaxf(mrun[qc], pm);
    float aS = exp2f(mrun[qc] - ms);
    float aP = exp2f(pm - ms);
    float ls = lrun[qc] * aS + pl * aP;
    scale[qc] = aS / ls;
  }
  // write scaled f32 acc to ob region (qs, ks) with row-XOR swizzle
  char* obw = SMc + qs * 16384 + ks * 32768;
#pragma unroll
  for (int qc = 0; qc < 2; qc++)
#pragma unroll
    for (int df = 0; df < 8; df++) {
      f32x4 v = acc[qc][df] * scale[qc];
      int r = qc * 16 + r16;
      int u = df * 4 + g;
      int up = u ^ ((r & 7) << 2);
      *(f32x4*)(obw + r * 512 + up * 16) = v;
    }
  __syncthreads();
  // readout: sum ks0+ks1 copies, convert, coalesced store
#pragma unroll
  for (int it = 0; it < 8; it++) {
    int item = it * 256 + tid;
    int qs2 = item >> 10, rem = item & 1023;
    int r = rem >> 5, u = rem & 31;
    int up = u ^ ((r & 7) << 2);
    f32x4 a = *(const f32x4*)(SMc + qs2 * 16384 + r * 512 + up * 16);
    f32x4 b = *(const f32x4*)(SMc + 32768 + qs2 * 16384 + r * 512 + up * 16);
    f32x4 sSum = a + b;
    uint2 pk;
    pk.x = cvtpk(sSum[0], sSum[1]);
    pk.y = cvtpk(sSum[2], sSum[3]);
    *(uint2*)(O + (size_t)(q0 + qs2 * 32 + r) * 2048 + h * 128 + u * 4) = pk;
  }
}

extern "C" void kernel_launch(void* const* d_in, const int* in_sizes, int n_in,
                              void* d_out, int out_size, void* d_ws, size_t ws_size,
                              hipStream_t stream) {
  const float* hidden = (const float*)d_in[0];
  const float* sinT = (const float*)d_in[1];
  const float* cosT = (const float*)d_in[2];
  // d_in[3] = mask (bool tril) — causal hardcoded
  const float* Wq = (const float*)d_in[4];
  const float* Wk = (const float*)d_in[5];
  const float* Wv = (const float*)d_in[6];
  const float* Wo = (const float*)d_in[7];
  const float* qsc = (const float*)d_in[8];
  const float* ksc = (const float*)d_in[9];
  float* out = (float*)d_out;

  char* ws = (char*)d_ws;
  u16* Xb   = (u16*)(ws + 0);          // [4096][2048]      16.78 MB
  u16* Bqkv = (u16*)(ws + 16777216);   // [3072][2048]      12.58 MB
  u16* Wot  = (u16*)(ws + 29360128);   // [2048][2048]       8.39 MB
  u16* Qraw = (u16*)(ws + 37748736);   // [4096][2048]      16.78 MB
  u16* Kraw = (u16*)(ws + 54525952);   // [4096][512]        4.19 MB
  u16* Vt   = (u16*)(ws + 58720256);   // [512][4096]        4.19 MB
  u16* Oat  = (u16*)(ws + 62914560);   // [4096][2048]      16.78 MB  (end 79.7 MB)

  k_cvt<<<dim3(4096), dim3(256), 0, stream>>>(hidden, Xb);
  k_transpose_cvt<<<dim3(64, 64), dim3(256), 0, stream>>>(Wq, Bqkv, 2048, 2048);
  k_transpose_cvt<<<dim3(16, 64), dim3(256), 0, stream>>>(Wk, Bqkv + 2048 * 2048, 2048, 512);
  k_transpose_cvt<<<dim3(16, 64), dim3(256), 0, stream>>>(Wv, Bqkv + 2560 * 2048, 2048, 512);
  k_transpose_cvt<<<dim3(64, 64), dim3(256), 0, stream>>>(Wo, Wot, 2048, 2048);

  k_gemm<<<dim3(24, 32), dim3(256), 0, stream>>>(Xb, Bqkv, Qraw, Kraw, Vt, (float*)nullptr,
                                                 4096, 3072, 2048, 0);
  k_normrope<<<dim3(4096, 5), dim3(256), 0, stream>>>(Qraw, Kraw, sinT, cosT, qsc, ksc);
  k_attn<<<dim3(1024), dim3(256), 0, stream>>>(Qraw, Kraw, Vt, Oat);
  k_gemm<<<dim3(16, 32), dim3(256), 0, stream>>>(Oat, Wot, (u16*)nullptr, (u16*)nullptr, (u16*)nullptr,
                                                 out, 4096, 2048, 2048, 1);
}